// Round 2
// baseline (407.636 us; speedup 1.0000x reference)
//
#include <hip/hip_runtime.h>

#define CH 128
#define OUTC 10
#define NB 256            // buckets (dst >> 9), only ceil(N/512) used
#define BCAP 10240        // per-bucket pair capacity (avg ~8192, >22 sigma margin)
#define PCHUNK 2048       // edges per partition block
#define PQ2 132           // LDS pitch in bf16 (dword stride 66 -> 2-way bank alias = free)
#define FBM 64            // rows per fused-layer block

typedef __attribute__((ext_vector_type(8))) short short8;
typedef __attribute__((ext_vector_type(4))) short short4v;
typedef __attribute__((ext_vector_type(16))) float f32x16;
typedef __attribute__((ext_vector_type(2))) float f32x2;

// ---------------------------------------------------------------- helpers

__device__ inline unsigned short f2bf(float f) {
    unsigned u = __builtin_bit_cast(unsigned, f);
    u += 0x7fffu + ((u >> 16) & 1u);   // RNE
    return (unsigned short)(u >> 16);
}
__device__ inline float bflo(unsigned u) { return __builtin_bit_cast(float, u << 16); }
__device__ inline float bfhi(unsigned u) { return __builtin_bit_cast(float, u & 0xffff0000u); }

// packed bf16 pair -> f32x2 (lshl / and, then one packed add on the consumer)
__device__ inline f32x2 bf2(unsigned u) {
    return (f32x2){__builtin_bit_cast(float, u << 16),
                   __builtin_bit_cast(float, u & 0xffff0000u)};
}

__device__ inline void acc8(f32x2* a, const uint4& v) {
    a[0] += bf2(v.x);
    a[1] += bf2(v.y);
    a[2] += bf2(v.z);
    a[3] += bf2(v.w);
}

// ---------------------------------------------------------------- mega prep: edge partition + x->bf16 + w-swizzle + pooled zero
// Block ranges (independent work, no cross-range deps):
//   [0, nPartBlk)                 : edge partition (bucketCnt pre-zeroed via memset)
//   [nPartBlk, +nConvBlk)         : x -> bf16
//   [.., +384)                    : weights -> MFMA-frag-swizzled bf16
//   [.., +nZeroBlk)               : zero pooled accumulator

struct WPtrs { const float* s[6]; unsigned short* d[6]; };

__global__ void prep_part_kernel(const int* __restrict__ src, const int* __restrict__ dst,
                                 int* __restrict__ bucketCnt, unsigned* __restrict__ pairs, int E,
                                 int nPartBlk,
                                 const float4* __restrict__ x4, uint2* __restrict__ xb, int n4,
                                 int nConvBlk, WPtrs p,
                                 uint4* __restrict__ pooled4, int nPooled4) {
    __shared__ int hist[NB];
    __shared__ int base[NB];
    __shared__ int cur[NB];
    int tid = threadIdx.x;   // 256
    int b = blockIdx.x;

    if (b < nPartBlk) {
        int e0 = b * PCHUNK;
        hist[tid] = 0;
        __syncthreads();
        #pragma unroll
        for (int i = 0; i < PCHUNK / 256; ++i) {
            int e = e0 + tid + i * 256;
            if (e < E) atomicAdd(&hist[dst[e] >> 9], 1);
        }
        __syncthreads();
        {
            int c = hist[tid];
            base[tid] = (c > 0) ? atomicAdd(&bucketCnt[tid], c) : 0;
            cur[tid] = 0;
        }
        __syncthreads();
        #pragma unroll
        for (int i = 0; i < PCHUNK / 256; ++i) {
            int e = e0 + tid + i * 256;
            if (e < E) {
                int d = dst[e];
                int bkt = d >> 9;
                int pos = base[bkt] + atomicAdd(&cur[bkt], 1);
                if (pos < BCAP)
                    pairs[bkt * BCAP + pos] = ((unsigned)(d & 511) << 17) | (unsigned)src[e];
            }
        }
    } else if (b < nPartBlk + nConvBlk) {
        int i = (b - nPartBlk) * 256 + tid;
        if (i < n4) {
            float4 v = x4[i];
            uint2 o;
            o.x = (unsigned)f2bf(v.x) | ((unsigned)f2bf(v.y) << 16);
            o.y = (unsigned)f2bf(v.z) | ((unsigned)f2bf(v.w) << 16);
            xb[i] = o;
        }
    } else if (b < nPartBlk + nConvBlk + 384) {
        int bb = b - nPartBlk - nConvBlk;  // 0..383
        int m = bb >> 6;                   // matrix 0..5
        int i = (bb & 63) * 256 + tid;     // 0..16383
        int j = i & 7;
        int l = (i >> 3) & 63;
        int k0 = (i >> 9) & 7;
        int ct = (i >> 12) & 3;
        int k = k0 * 16 + ((l >> 5) << 3) + j;
        int nn = ct * 32 + (l & 31);
        p.d[m][i] = f2bf(p.s[m][k * CH + nn]);
    } else {
        int i = (b - nPartBlk - nConvBlk - 384) * 256 + tid;
        if (i < nPooled4) pooled4[i] = make_uint4(0, 0, 0, 0);
    }
}

// ---------------------------------------------------------------- CSR build (self-scans bucket counts)
// 512 threads (was 256): halves the serial per-block pair work; grid is
// only ~196 blocks (1/CU) so per-block latency is the whole kernel's latency.

__launch_bounds__(512)
__global__ void build_csr_kernel(const unsigned* __restrict__ pairs, const int* __restrict__ bucketCnt,
                                 int* __restrict__ offs, int* __restrict__ csr, int N) {
    __shared__ int bsm[NB];
    __shared__ int ldeg[512];
    __shared__ int s0[512], s1[512];
    __shared__ int lexc[512];
    __shared__ int lcur[512];
    __shared__ int lcsr[BCAP];

    int b = blockIdx.x;
    int node0 = b << 9;
    if (node0 >= N) return;
    int nLocal = min(512, N - node0);
    int tid = threadIdx.x;   // 512

    if (tid < NB) bsm[tid] = bucketCnt[tid];
    __syncthreads();
    for (int off = 1; off < NB; off <<= 1) {
        int t = 0;
        if (tid < NB) t = (tid >= off) ? bsm[tid - off] : 0;
        __syncthreads();
        if (tid < NB) bsm[tid] += t;
        __syncthreads();
    }
    int cnt = min(bucketCnt[b], BCAP);
    int gbase = bsm[b] - bucketCnt[b];

    ldeg[tid] = 0;
    __syncthreads();
    for (int i = tid; i < cnt; i += 512)
        atomicAdd(&ldeg[pairs[b * BCAP + i] >> 17], 1);
    __syncthreads();

    s0[tid] = ldeg[tid];
    __syncthreads();
    int* sp = s0; int* dp = s1;
    for (int off = 1; off < 512; off <<= 1) {
        dp[tid] = sp[tid] + ((tid >= off) ? sp[tid - off] : 0);
        __syncthreads();
        int* t = sp; sp = dp; dp = t;
    }
    {
        int ex = sp[tid] - ldeg[tid];
        lexc[tid] = ex;
        lcur[tid] = ex;
    }
    __syncthreads();

    for (int i = tid; i < cnt; i += 512) {
        unsigned w = pairs[b * BCAP + i];
        int ppos = atomicAdd(&lcur[w >> 17], 1);
        lcsr[ppos] = (int)(w & 0x1ffffu);
    }
    __syncthreads();

    for (int i = tid; i < cnt; i += 512) csr[gbase + i] = lcsr[i];
    for (int i = tid; i < nLocal; i += 512) offs[node0 + i] = gbase + lexc[i];
    if (tid == 0 && node0 + nLocal == N) offs[N] = gbase + cnt;
}

// ---------------------------------------------------------------- fused GIN layer: gather -> LDS -> MFMA MLP -> write | pool
// BM=64, 512 threads, 16.9 KB LDS, one 32x32 MFMA tile per wave (acc=16 VGPR).
// Gather: each 16-lane group processes BOTH of its rows (grp, grp+32)
// CONCURRENTLY — 8 gather loads (2 KB) in flight per wave instead of 4, and
// the per-wave trip count is max(ceil(dA/4),ceil(dB/4)) instead of the sum.
// Per-node accumulation order (self, then CSR-ascending) is unchanged ->
// bit-exact per node vs the previous kernel.

template <int L, int RELU, int POOL>
__launch_bounds__(512)
__global__ void fused_gin_kernel(const uint4* __restrict__ h4,
                                 const int* __restrict__ offs, const int* __restrict__ csr,
                                 const unsigned short* __restrict__ w1s, const float* __restrict__ b1,
                                 const unsigned short* __restrict__ w2s, const float* __restrict__ b2,
                                 unsigned short* __restrict__ hout,
                                 const int* __restrict__ batch, float* __restrict__ pooled,
                                 int n) {
    __shared__ __align__(16) unsigned short zs[FBM * PQ2];   // 16.9 KB

    int tid = threadIdx.x;
    int row0 = blockIdx.x * FBM;

    // ---- gather phase: z = h[node] + sum h[src], fp32 accum -> bf16 into LDS
    {
        int gl = tid & 15;
        int grp = tid >> 4;    // 0..31
        int nodeA = row0 + grp;
        int nodeB = row0 + grp + 32;
        bool hvA = nodeA < n, hvB = nodeB < n;

        f32x2 a[4], bacc[4];
        #pragma unroll
        for (int i = 0; i < 4; ++i) { a[i] = (f32x2){0.f, 0.f}; bacc[i] = (f32x2){0.f, 0.f}; }

        int eA = 0, endA = 0, eB = 0, endB = 0;
        if (hvA) { eA = offs[nodeA]; endA = offs[nodeA + 1]; }
        if (hvB) { eB = offs[nodeB]; endB = offs[nodeB + 1]; }

        // self terms (both loads issued before either accumulate)
        {
            uint4 sA = make_uint4(0, 0, 0, 0), sB = make_uint4(0, 0, 0, 0);
            if (hvA) sA = h4[nodeA * 16 + gl];
            if (hvB) sB = h4[nodeB * 16 + gl];
            acc8(a, sA); acc8(bacc, sB);
        }

        // main loop: both streams' csr loads, then all 8 gathers, then accs
        while (true) {
            bool cA = (eA + 4 <= endA);
            bool cB = (eB + 4 <= endB);
            if (!(cA || cB)) break;
            int sA0 = 0, sA1 = 0, sA2 = 0, sA3 = 0, sB0 = 0, sB1 = 0, sB2 = 0, sB3 = 0;
            uint4 vA0 = make_uint4(0,0,0,0), vA1 = vA0, vA2 = vA0, vA3 = vA0;
            uint4 vB0 = vA0, vB1 = vA0, vB2 = vA0, vB3 = vA0;
            if (cA) { sA0 = csr[eA]; sA1 = csr[eA + 1]; sA2 = csr[eA + 2]; sA3 = csr[eA + 3]; }
            if (cB) { sB0 = csr[eB]; sB1 = csr[eB + 1]; sB2 = csr[eB + 2]; sB3 = csr[eB + 3]; }
            if (cA) {
                vA0 = h4[sA0 * 16 + gl]; vA1 = h4[sA1 * 16 + gl];
                vA2 = h4[sA2 * 16 + gl]; vA3 = h4[sA3 * 16 + gl];
            }
            if (cB) {
                vB0 = h4[sB0 * 16 + gl]; vB1 = h4[sB1 * 16 + gl];
                vB2 = h4[sB2 * 16 + gl]; vB3 = h4[sB3 * 16 + gl];
            }
            if (cA) { acc8(a, vA0); acc8(a, vA1); acc8(a, vA2); acc8(a, vA3); eA += 4; }
            if (cB) { acc8(bacc, vB0); acc8(bacc, vB1); acc8(bacc, vB2); acc8(bacc, vB3); eB += 4; }
        }
        // tails (<=3 each), A/B overlapped; adding packed zeros is exact
        while (eA < endA || eB < endB) {
            bool dA = eA < endA, dB = eB < endB;
            uint4 tA = make_uint4(0, 0, 0, 0), tB = make_uint4(0, 0, 0, 0);
            if (dA) tA = h4[csr[eA] * 16 + gl];
            if (dB) tB = h4[csr[eB] * 16 + gl];
            acc8(a, tA); acc8(bacc, tB);
            eA += dA; eB += dB;
        }

        unsigned o0 = (unsigned)f2bf(a[0][0]) | ((unsigned)f2bf(a[0][1]) << 16);
        unsigned o1 = (unsigned)f2bf(a[1][0]) | ((unsigned)f2bf(a[1][1]) << 16);
        unsigned o2 = (unsigned)f2bf(a[2][0]) | ((unsigned)f2bf(a[2][1]) << 16);
        unsigned o3 = (unsigned)f2bf(a[3][0]) | ((unsigned)f2bf(a[3][1]) << 16);
        *(uint2*)&zs[grp * PQ2 + gl * 8]     = make_uint2(o0, o1);
        *(uint2*)&zs[grp * PQ2 + gl * 8 + 4] = make_uint2(o2, o3);

        o0 = (unsigned)f2bf(bacc[0][0]) | ((unsigned)f2bf(bacc[0][1]) << 16);
        o1 = (unsigned)f2bf(bacc[1][0]) | ((unsigned)f2bf(bacc[1][1]) << 16);
        o2 = (unsigned)f2bf(bacc[2][0]) | ((unsigned)f2bf(bacc[2][1]) << 16);
        o3 = (unsigned)f2bf(bacc[3][0]) | ((unsigned)f2bf(bacc[3][1]) << 16);
        *(uint2*)&zs[(grp + 32) * PQ2 + gl * 8]     = make_uint2(o0, o1);
        *(uint2*)&zs[(grp + 32) * PQ2 + gl * 8 + 4] = make_uint2(o2, o3);
    }
    __syncthreads();

    int wv = tid >> 6;         // 0..7
    int lane = tid & 63;
    int l31 = lane & 31;
    int kh = lane >> 5;
    int rt = wv & 1;           // 2 row tiles of 32
    int ct = wv >> 1;          // 4 col tiles of 32
    int arow = rt * 32 + l31;

    // ---- matmul 1: t = relu(z @ w1 + b1)
    f32x16 acc;
    {
        float bv = b1[ct * 32 + l31];
        #pragma unroll
        for (int r = 0; r < 16; ++r) acc[r] = bv;
    }
    #pragma unroll
    for (int k0 = 0; k0 < 8; ++k0) {
        short8 afr;
        {
            short4v lo = *(const short4v*)&zs[arow * PQ2 + k0 * 16 + kh * 8];
            short4v hi = *(const short4v*)&zs[arow * PQ2 + k0 * 16 + kh * 8 + 4];
            afr = (short8){lo[0], lo[1], lo[2], lo[3], hi[0], hi[1], hi[2], hi[3]};
        }
        short8 bfr = *(const short8*)&w1s[(((ct * 8 + k0) * 64) + lane) * 8];
        acc = __builtin_amdgcn_mfma_f32_32x32x16_bf16(afr, bfr, acc, 0, 0, 0);
    }
    __syncthreads();

    #pragma unroll
    for (int reg = 0; reg < 16; ++reg) {
        int crow = (reg & 3) + 8 * (reg >> 2) + 4 * kh;
        zs[(rt * 32 + crow) * PQ2 + ct * 32 + l31] = f2bf(fmaxf(acc[reg], 0.f));
    }
    __syncthreads();

    // ---- matmul 2: h = t @ w2 + b2 [+ relu]
    {
        float bv = b2[ct * 32 + l31];
        #pragma unroll
        for (int r = 0; r < 16; ++r) acc[r] = bv;
    }
    #pragma unroll
    for (int k0 = 0; k0 < 8; ++k0) {
        short8 afr;
        {
            short4v lo = *(const short4v*)&zs[arow * PQ2 + k0 * 16 + kh * 8];
            short4v hi = *(const short4v*)&zs[arow * PQ2 + k0 * 16 + kh * 8 + 4];
            afr = (short8){lo[0], lo[1], lo[2], lo[3], hi[0], hi[1], hi[2], hi[3]};
        }
        short8 bfr = *(const short8*)&w2s[(((ct * 8 + k0) * 64) + lane) * 8];
        acc = __builtin_amdgcn_mfma_f32_32x32x16_bf16(afr, bfr, acc, 0, 0, 0);
    }
    __syncthreads();

    #pragma unroll
    for (int reg = 0; reg < 16; ++reg) {
        int crow = (reg & 3) + 8 * (reg >> 2) + 4 * kh;
        float v = acc[reg];
        if (RELU) v = fmaxf(v, 0.f);
        zs[(rt * 32 + crow) * PQ2 + ct * 32 + l31] = f2bf(v);
    }
    __syncthreads();

    if (!POOL) {
        for (int i = tid; i < FBM * 16; i += 512) {
            int r = i >> 4, c = i & 15;
            int row = row0 + r;
            if (row < n) {
                uint2 a2 = *(const uint2*)&zs[r * PQ2 + c * 8];
                uint2 b2v = *(const uint2*)&zs[r * PQ2 + c * 8 + 4];
                ((uint4*)hout)[row * 16 + c] = make_uint4(a2.x, a2.y, b2v.x, b2v.y);
            }
        }
    } else {
        // pool epilogue from LDS tile (batch sorted)
        int c2 = tid & 63;      // uint column (ch 2*c2, 2*c2+1)
        int rs = tid >> 6;      // 0..7
        float a0 = 0.f, a1 = 0.f;
        int prevg = -1;
        #pragma unroll
        for (int i = 0; i < FBM / 8; ++i) {
            int r = rs + 8 * i;
            int row = row0 + r;
            if (row >= n) break;
            int g = batch[row];
            if (g != prevg) {
                if (prevg >= 0) {
                    atomicAdd(&pooled[prevg * CH + 2 * c2], a0);
                    atomicAdd(&pooled[prevg * CH + 2 * c2 + 1], a1);
                }
                prevg = g; a0 = 0.f; a1 = 0.f;
            }
            unsigned v = *(const unsigned*)&zs[r * PQ2 + c2 * 2];
            a0 += bflo(v); a1 += bfhi(v);
        }
        if (prevg >= 0) {
            atomicAdd(&pooled[prevg * CH + 2 * c2], a0);
            atomicAdd(&pooled[prevg * CH + 2 * c2 + 1], a1);
        }
    }
}

// ---------------------------------------------------------------- final linear

__global__ void final_linear_kernel(const float* __restrict__ pooled, const float* __restrict__ lin_w,
                                    const float* __restrict__ lin_b, float* __restrict__ out) {
    int g = blockIdx.x;
    int tid = threadIdx.x;   // 128
    __shared__ float pl[CH];
    pl[tid] = pooled[g * CH + tid];
    __syncthreads();
    if (tid < OUTC) {
        float a = lin_b[tid];
        #pragma unroll 16
        for (int c = 0; c < CH; ++c) a = fmaf(pl[c], lin_w[c * OUTC + tid], a);
        out[g * OUTC + tid] = a;
    }
}

// ---------------------------------------------------------------- launch

static inline size_t aln(size_t x) { return (x + 255) & ~size_t(255); }

extern "C" void kernel_launch(void* const* d_in, const int* in_sizes, int n_in,
                              void* d_out, int out_size, void* d_ws, size_t ws_size,
                              hipStream_t stream) {
    const float* x      = (const float*)d_in[0];
    const int*   ei     = (const int*)d_in[1];
    const int*   batch  = (const int*)d_in[2];
    const float* w1[3]  = {(const float*)d_in[3], (const float*)d_in[7],  (const float*)d_in[11]};
    const float* b1[3]  = {(const float*)d_in[4], (const float*)d_in[8],  (const float*)d_in[12]};
    const float* w2[3]  = {(const float*)d_in[5], (const float*)d_in[9],  (const float*)d_in[13]};
    const float* b2[3]  = {(const float*)d_in[6], (const float*)d_in[10], (const float*)d_in[14]};
    const float* lin_w  = (const float*)d_in[15];
    const float* lin_b  = (const float*)d_in[16];
    float* out = (float*)d_out;

    int E = in_sizes[1] / 2;
    int N = in_sizes[2];
    int n_graphs = out_size / OUTC;
    const int* src = ei;
    const int* dst = ei + E;

    char* p = (char*)d_ws;
    int* bucketCnt  = (int*)p; p += aln(NB * 4);
    unsigned* pairs = (unsigned*)p; p += aln((size_t)NB * BCAP * 4);
    int* offs       = (int*)p; p += aln((size_t)(N + 1) * 4);
    int* csr        = (int*)p; p += aln((size_t)E * 4);
    unsigned short* xb = (unsigned short*)p; p += aln((size_t)N * CH * 2);
    unsigned short* hA = (unsigned short*)p; p += aln((size_t)N * CH * 2);
    unsigned short* hB = (unsigned short*)p; p += aln((size_t)N * CH * 2);
    float* pooled = (float*)p; p += aln((size_t)n_graphs * CH * 4);
    unsigned short* wt[6];
    for (int i = 0; i < 6; ++i) { wt[i] = (unsigned short*)p; p += aln((size_t)CH * CH * 2); }
    (void)ws_size; (void)n_in;

    // bucketCnt must be zero before partition blocks run
    hipMemsetAsync(bucketCnt, 0, NB * 4, stream);

    // mega-prep: partition + convert x + swizzle weights + zero pooled
    int n4 = N * CH / 4;
    int nConvBlk = (n4 + 255) / 256;
    int nPartBlk = (E + PCHUNK - 1) / PCHUNK;
    int nPooled4 = n_graphs * CH / 4;
    int nZeroBlk = (nPooled4 + 255) / 256;
    WPtrs wp;
    for (int l = 0; l < 3; ++l) {
        wp.s[2 * l] = w1[l];     wp.d[2 * l] = wt[2 * l];
        wp.s[2 * l + 1] = w2[l]; wp.d[2 * l + 1] = wt[2 * l + 1];
    }
    prep_part_kernel<<<nPartBlk + nConvBlk + 384 + nZeroBlk, 256, 0, stream>>>(
        src, dst, bucketCnt, pairs, E, nPartBlk,
        (const float4*)x, (uint2*)xb, n4, nConvBlk, wp,
        (uint4*)pooled, nPooled4);

    build_csr_kernel<<<NB, 512, 0, stream>>>(pairs, bucketCnt, offs, csr, N);

    int fblk = (N + FBM - 1) / FBM;

    // three fused GIN layers
    fused_gin_kernel<0, 1, 0><<<fblk, 512, 0, stream>>>((const uint4*)xb, offs, csr,
        wt[0], b1[0], wt[1], b2[0], hA, batch, pooled, N);
    fused_gin_kernel<1, 1, 0><<<fblk, 512, 0, stream>>>((const uint4*)hA, offs, csr,
        wt[2], b1[1], wt[3], b2[1], hB, batch, pooled, N);
    fused_gin_kernel<2, 0, 1><<<fblk, 512, 0, stream>>>((const uint4*)hB, offs, csr,
        wt[4], b1[2], wt[5], b2[2], (unsigned short*)nullptr, batch, pooled, N);

    final_linear_kernel<<<n_graphs, CH, 0, stream>>>(pooled, lin_w, lin_b, out);
}

// Round 3
// 372.933 us; speedup vs baseline: 1.0931x; 1.0931x over previous
//
#include <hip/hip_runtime.h>

#define CH 128
#define OUTC 10
#define NB 256            // buckets (dst >> 9), only ceil(N/512) used
#define BCAP 10240        // per-bucket pair capacity (avg ~8192, >22 sigma margin)
#define PCHUNK 2048       // edges per partition block
#define PQ2 132           // LDS pitch in bf16 (dword stride 66 -> 2-way bank alias = free)
#define FBM 64            // rows per fused-layer block

typedef __attribute__((ext_vector_type(8))) short short8;
typedef __attribute__((ext_vector_type(4))) short short4v;
typedef __attribute__((ext_vector_type(16))) float f32x16;
typedef __attribute__((ext_vector_type(2))) float f32x2;

// ---------------------------------------------------------------- helpers

__device__ inline unsigned short f2bf(float f) {
    unsigned u = __builtin_bit_cast(unsigned, f);
    u += 0x7fffu + ((u >> 16) & 1u);   // RNE
    return (unsigned short)(u >> 16);
}
__device__ inline float bflo(unsigned u) { return __builtin_bit_cast(float, u << 16); }
__device__ inline float bfhi(unsigned u) { return __builtin_bit_cast(float, u & 0xffff0000u); }

// packed bf16 pair -> f32x2 (lshl / and, then one packed add on the consumer)
__device__ inline f32x2 bf2(unsigned u) {
    return (f32x2){__builtin_bit_cast(float, u << 16),
                   __builtin_bit_cast(float, u & 0xffff0000u)};
}

__device__ inline void acc8(f32x2* a, const uint4& v) {
    a[0] += bf2(v.x);
    a[1] += bf2(v.y);
    a[2] += bf2(v.z);
    a[3] += bf2(v.w);
}

// ---------------------------------------------------------------- mega prep: edge partition + x->bf16 + w-swizzle + pooled zero

struct WPtrs { const float* s[6]; unsigned short* d[6]; };

__global__ void prep_part_kernel(const int* __restrict__ src, const int* __restrict__ dst,
                                 int* __restrict__ bucketCnt, unsigned* __restrict__ pairs, int E,
                                 int nPartBlk,
                                 const float4* __restrict__ x4, uint2* __restrict__ xb, int n4,
                                 int nConvBlk, WPtrs p,
                                 uint4* __restrict__ pooled4, int nPooled4) {
    __shared__ int hist[NB];
    __shared__ int base[NB];
    __shared__ int cur[NB];
    int tid = threadIdx.x;   // 256
    int b = blockIdx.x;

    if (b < nPartBlk) {
        int e0 = b * PCHUNK;
        hist[tid] = 0;
        __syncthreads();
        #pragma unroll
        for (int i = 0; i < PCHUNK / 256; ++i) {
            int e = e0 + tid + i * 256;
            if (e < E) atomicAdd(&hist[dst[e] >> 9], 1);
        }
        __syncthreads();
        {
            int c = hist[tid];
            base[tid] = (c > 0) ? atomicAdd(&bucketCnt[tid], c) : 0;
            cur[tid] = 0;
        }
        __syncthreads();
        #pragma unroll
        for (int i = 0; i < PCHUNK / 256; ++i) {
            int e = e0 + tid + i * 256;
            if (e < E) {
                int d = dst[e];
                int bkt = d >> 9;
                int pos = base[bkt] + atomicAdd(&cur[bkt], 1);
                if (pos < BCAP)
                    pairs[bkt * BCAP + pos] = ((unsigned)(d & 511) << 17) | (unsigned)src[e];
            }
        }
    } else if (b < nPartBlk + nConvBlk) {
        int i = (b - nPartBlk) * 256 + tid;
        if (i < n4) {
            float4 v = x4[i];
            uint2 o;
            o.x = (unsigned)f2bf(v.x) | ((unsigned)f2bf(v.y) << 16);
            o.y = (unsigned)f2bf(v.z) | ((unsigned)f2bf(v.w) << 16);
            xb[i] = o;
        }
    } else if (b < nPartBlk + nConvBlk + 384) {
        int bb = b - nPartBlk - nConvBlk;  // 0..383
        int m = bb >> 6;                   // matrix 0..5
        int i = (bb & 63) * 256 + tid;     // 0..16383
        int j = i & 7;
        int l = (i >> 3) & 63;
        int k0 = (i >> 9) & 7;
        int ct = (i >> 12) & 3;
        int k = k0 * 16 + ((l >> 5) << 3) + j;
        int nn = ct * 32 + (l & 31);
        p.d[m][i] = f2bf(p.s[m][k * CH + nn]);
    } else {
        int i = (b - nPartBlk - nConvBlk - 384) * 256 + tid;
        if (i < nPooled4) pooled4[i] = make_uint4(0, 0, 0, 0);
    }
}

// ---------------------------------------------------------------- CSR build (self-scans bucket counts)

__launch_bounds__(512)
__global__ void build_csr_kernel(const unsigned* __restrict__ pairs, const int* __restrict__ bucketCnt,
                                 int* __restrict__ offs, int* __restrict__ csr, int N) {
    __shared__ int bsm[NB];
    __shared__ int ldeg[512];
    __shared__ int s0[512], s1[512];
    __shared__ int lexc[512];
    __shared__ int lcur[512];
    __shared__ int lcsr[BCAP];

    int b = blockIdx.x;
    int node0 = b << 9;
    if (node0 >= N) return;
    int nLocal = min(512, N - node0);
    int tid = threadIdx.x;   // 512

    if (tid < NB) bsm[tid] = bucketCnt[tid];
    __syncthreads();
    for (int off = 1; off < NB; off <<= 1) {
        int t = 0;
        if (tid < NB) t = (tid >= off) ? bsm[tid - off] : 0;
        __syncthreads();
        if (tid < NB) bsm[tid] += t;
        __syncthreads();
    }
    int cnt = min(bucketCnt[b], BCAP);
    int gbase = bsm[b] - bucketCnt[b];

    ldeg[tid] = 0;
    __syncthreads();
    for (int i = tid; i < cnt; i += 512)
        atomicAdd(&ldeg[pairs[b * BCAP + i] >> 17], 1);
    __syncthreads();

    s0[tid] = ldeg[tid];
    __syncthreads();
    int* sp = s0; int* dp = s1;
    for (int off = 1; off < 512; off <<= 1) {
        dp[tid] = sp[tid] + ((tid >= off) ? sp[tid - off] : 0);
        __syncthreads();
        int* t = sp; sp = dp; dp = t;
    }
    {
        int ex = sp[tid] - ldeg[tid];
        lexc[tid] = ex;
        lcur[tid] = ex;
    }
    __syncthreads();

    for (int i = tid; i < cnt; i += 512) {
        unsigned w = pairs[b * BCAP + i];
        int ppos = atomicAdd(&lcur[w >> 17], 1);
        lcsr[ppos] = (int)(w & 0x1ffffu);
    }
    __syncthreads();

    for (int i = tid; i < cnt; i += 512) csr[gbase + i] = lcsr[i];
    for (int i = tid; i < nLocal; i += 512) offs[node0 + i] = gbase + lexc[i];
    if (tid == 0 && node0 + nLocal == N) offs[N] = gbase + cnt;
}

// ---------------------------------------------------------------- fused GIN layer: gather -> LDS -> MFMA MLP -> write | pool
// BM=64, 512 threads, 16.9 KB LDS, one 32x32 MFMA tile per wave (acc=16 VGPR).
// Gather: round-0 control flow (two rows per group, sequential) BUT with the
// csr index loads software-pipelined one batch ahead: issue h4 data loads for
// batch k (indices already in registers), then issue csr loads for batch k+1,
// THEN accumulate batch k. The next-batch index latency hides fully under the
// current data wait -> serial chain per batch drops from ~2 latency hops to 1.
// No predication added (round-1/2 lesson: exec-mask churn costs more than it
// hides). Accumulation order bit-identical to round-0.

template <int L, int RELU, int POOL>
__launch_bounds__(512)
__global__ void fused_gin_kernel(const uint4* __restrict__ h4,
                                 const int* __restrict__ offs, const int* __restrict__ csr,
                                 const unsigned short* __restrict__ w1s, const float* __restrict__ b1,
                                 const unsigned short* __restrict__ w2s, const float* __restrict__ b2,
                                 unsigned short* __restrict__ hout,
                                 const int* __restrict__ batch, float* __restrict__ pooled,
                                 int n) {
    __shared__ __align__(16) unsigned short zs[FBM * PQ2];   // 16.9 KB

    int tid = threadIdx.x;
    int row0 = blockIdx.x * FBM;

    // ---- gather phase: z = h[node] + sum h[src], fp32 accum -> bf16 into LDS
    {
        int gl = tid & 15;
        int grp = tid >> 4;    // 0..31
        #pragma unroll
        for (int it = 0; it < 2; ++it) {
            int rr = grp + 32 * it;
            int node = row0 + rr;
            unsigned o0 = 0, o1 = 0, o2 = 0, o3 = 0;
            if (node < n) {
                int beg = offs[node], end = offs[node + 1];
                f32x2 a[4];
                uint4 self = h4[node * 16 + gl];
                a[0] = bf2(self.x);
                a[1] = bf2(self.y);
                a[2] = bf2(self.z);
                a[3] = bf2(self.w);
                int e = beg;
                int elim = beg + ((end - beg) & ~3);   // end of full batches
                if (e < elim) {
                    // prologue: indices for batch 0
                    int s0 = csr[e], s1 = csr[e + 1], s2 = csr[e + 2], s3 = csr[e + 3];
                    // steady state: data[k] loads, then idx[k+1] loads, then acc[k]
                    for (; e + 8 <= elim; e += 4) {
                        uint4 v0 = h4[s0 * 16 + gl];
                        uint4 v1 = h4[s1 * 16 + gl];
                        uint4 v2 = h4[s2 * 16 + gl];
                        uint4 v3 = h4[s3 * 16 + gl];
                        int t0 = csr[e + 4], t1 = csr[e + 5], t2 = csr[e + 6], t3 = csr[e + 7];
                        acc8(a, v0); acc8(a, v1); acc8(a, v2); acc8(a, v3);
                        s0 = t0; s1 = t1; s2 = t2; s3 = t3;
                    }
                    // epilogue: last full batch (indices already in registers)
                    {
                        uint4 v0 = h4[s0 * 16 + gl];
                        uint4 v1 = h4[s1 * 16 + gl];
                        uint4 v2 = h4[s2 * 16 + gl];
                        uint4 v3 = h4[s3 * 16 + gl];
                        acc8(a, v0); acc8(a, v1); acc8(a, v2); acc8(a, v3);
                        e += 4;
                    }
                }
                // tail (<=3 edges)
                for (; e < end; ++e) {
                    uint4 v = h4[csr[e] * 16 + gl];
                    acc8(a, v);
                }
                o0 = (unsigned)f2bf(a[0][0]) | ((unsigned)f2bf(a[0][1]) << 16);
                o1 = (unsigned)f2bf(a[1][0]) | ((unsigned)f2bf(a[1][1]) << 16);
                o2 = (unsigned)f2bf(a[2][0]) | ((unsigned)f2bf(a[2][1]) << 16);
                o3 = (unsigned)f2bf(a[3][0]) | ((unsigned)f2bf(a[3][1]) << 16);
            }
            *(uint2*)&zs[rr * PQ2 + gl * 8]     = make_uint2(o0, o1);
            *(uint2*)&zs[rr * PQ2 + gl * 8 + 4] = make_uint2(o2, o3);
        }
    }
    __syncthreads();

    int wv = tid >> 6;         // 0..7
    int lane = tid & 63;
    int l31 = lane & 31;
    int kh = lane >> 5;
    int rt = wv & 1;           // 2 row tiles of 32
    int ct = wv >> 1;          // 4 col tiles of 32
    int arow = rt * 32 + l31;

    // ---- matmul 1: t = relu(z @ w1 + b1)
    f32x16 acc;
    {
        float bv = b1[ct * 32 + l31];
        #pragma unroll
        for (int r = 0; r < 16; ++r) acc[r] = bv;
    }
    #pragma unroll
    for (int k0 = 0; k0 < 8; ++k0) {
        short8 afr;
        {
            short4v lo = *(const short4v*)&zs[arow * PQ2 + k0 * 16 + kh * 8];
            short4v hi = *(const short4v*)&zs[arow * PQ2 + k0 * 16 + kh * 8 + 4];
            afr = (short8){lo[0], lo[1], lo[2], lo[3], hi[0], hi[1], hi[2], hi[3]};
        }
        short8 bfr = *(const short8*)&w1s[(((ct * 8 + k0) * 64) + lane) * 8];
        acc = __builtin_amdgcn_mfma_f32_32x32x16_bf16(afr, bfr, acc, 0, 0, 0);
    }
    __syncthreads();

    #pragma unroll
    for (int reg = 0; reg < 16; ++reg) {
        int crow = (reg & 3) + 8 * (reg >> 2) + 4 * kh;
        zs[(rt * 32 + crow) * PQ2 + ct * 32 + l31] = f2bf(fmaxf(acc[reg], 0.f));
    }
    __syncthreads();

    // ---- matmul 2: h = t @ w2 + b2 [+ relu]
    {
        float bv = b2[ct * 32 + l31];
        #pragma unroll
        for (int r = 0; r < 16; ++r) acc[r] = bv;
    }
    #pragma unroll
    for (int k0 = 0; k0 < 8; ++k0) {
        short8 afr;
        {
            short4v lo = *(const short4v*)&zs[arow * PQ2 + k0 * 16 + kh * 8];
            short4v hi = *(const short4v*)&zs[arow * PQ2 + k0 * 16 + kh * 8 + 4];
            afr = (short8){lo[0], lo[1], lo[2], lo[3], hi[0], hi[1], hi[2], hi[3]};
        }
        short8 bfr = *(const short8*)&w2s[(((ct * 8 + k0) * 64) + lane) * 8];
        acc = __builtin_amdgcn_mfma_f32_32x32x16_bf16(afr, bfr, acc, 0, 0, 0);
    }
    __syncthreads();

    #pragma unroll
    for (int reg = 0; reg < 16; ++reg) {
        int crow = (reg & 3) + 8 * (reg >> 2) + 4 * kh;
        float v = acc[reg];
        if (RELU) v = fmaxf(v, 0.f);
        zs[(rt * 32 + crow) * PQ2 + ct * 32 + l31] = f2bf(v);
    }
    __syncthreads();

    if (!POOL) {
        for (int i = tid; i < FBM * 16; i += 512) {
            int r = i >> 4, c = i & 15;
            int row = row0 + r;
            if (row < n) {
                uint2 a2 = *(const uint2*)&zs[r * PQ2 + c * 8];
                uint2 b2v = *(const uint2*)&zs[r * PQ2 + c * 8 + 4];
                ((uint4*)hout)[row * 16 + c] = make_uint4(a2.x, a2.y, b2v.x, b2v.y);
            }
        }
    } else {
        // pool epilogue from LDS tile (batch sorted)
        int c2 = tid & 63;      // uint column (ch 2*c2, 2*c2+1)
        int rs = tid >> 6;      // 0..7
        float a0 = 0.f, a1 = 0.f;
        int prevg = -1;
        #pragma unroll
        for (int i = 0; i < FBM / 8; ++i) {
            int r = rs + 8 * i;
            int row = row0 + r;
            if (row >= n) break;
            int g = batch[row];
            if (g != prevg) {
                if (prevg >= 0) {
                    atomicAdd(&pooled[prevg * CH + 2 * c2], a0);
                    atomicAdd(&pooled[prevg * CH + 2 * c2 + 1], a1);
                }
                prevg = g; a0 = 0.f; a1 = 0.f;
            }
            unsigned v = *(const unsigned*)&zs[r * PQ2 + c2 * 2];
            a0 += bflo(v); a1 += bfhi(v);
        }
        if (prevg >= 0) {
            atomicAdd(&pooled[prevg * CH + 2 * c2], a0);
            atomicAdd(&pooled[prevg * CH + 2 * c2 + 1], a1);
        }
    }
}

// ---------------------------------------------------------------- final linear

__global__ void final_linear_kernel(const float* __restrict__ pooled, const float* __restrict__ lin_w,
                                    const float* __restrict__ lin_b, float* __restrict__ out) {
    int g = blockIdx.x;
    int tid = threadIdx.x;   // 128
    __shared__ float pl[CH];
    pl[tid] = pooled[g * CH + tid];
    __syncthreads();
    if (tid < OUTC) {
        float a = lin_b[tid];
        #pragma unroll 16
        for (int c = 0; c < CH; ++c) a = fmaf(pl[c], lin_w[c * OUTC + tid], a);
        out[g * OUTC + tid] = a;
    }
}

// ---------------------------------------------------------------- launch

static inline size_t aln(size_t x) { return (x + 255) & ~size_t(255); }

extern "C" void kernel_launch(void* const* d_in, const int* in_sizes, int n_in,
                              void* d_out, int out_size, void* d_ws, size_t ws_size,
                              hipStream_t stream) {
    const float* x      = (const float*)d_in[0];
    const int*   ei     = (const int*)d_in[1];
    const int*   batch  = (const int*)d_in[2];
    const float* w1[3]  = {(const float*)d_in[3], (const float*)d_in[7],  (const float*)d_in[11]};
    const float* b1[3]  = {(const float*)d_in[4], (const float*)d_in[8],  (const float*)d_in[12]};
    const float* w2[3]  = {(const float*)d_in[5], (const float*)d_in[9],  (const float*)d_in[13]};
    const float* b2[3]  = {(const float*)d_in[6], (const float*)d_in[10], (const float*)d_in[14]};
    const float* lin_w  = (const float*)d_in[15];
    const float* lin_b  = (const float*)d_in[16];
    float* out = (float*)d_out;

    int E = in_sizes[1] / 2;
    int N = in_sizes[2];
    int n_graphs = out_size / OUTC;
    const int* src = ei;
    const int* dst = ei + E;

    char* p = (char*)d_ws;
    int* bucketCnt  = (int*)p; p += aln(NB * 4);
    unsigned* pairs = (unsigned*)p; p += aln((size_t)NB * BCAP * 4);
    int* offs       = (int*)p; p += aln((size_t)(N + 1) * 4);
    int* csr        = (int*)p; p += aln((size_t)E * 4);
    unsigned short* xb = (unsigned short*)p; p += aln((size_t)N * CH * 2);
    unsigned short* hA = (unsigned short*)p; p += aln((size_t)N * CH * 2);
    unsigned short* hB = (unsigned short*)p; p += aln((size_t)N * CH * 2);
    float* pooled = (float*)p; p += aln((size_t)n_graphs * CH * 4);
    unsigned short* wt[6];
    for (int i = 0; i < 6; ++i) { wt[i] = (unsigned short*)p; p += aln((size_t)CH * CH * 2); }
    (void)ws_size; (void)n_in;

    // bucketCnt must be zero before partition blocks run
    hipMemsetAsync(bucketCnt, 0, NB * 4, stream);

    // mega-prep: partition + convert x + swizzle weights + zero pooled
    int n4 = N * CH / 4;
    int nConvBlk = (n4 + 255) / 256;
    int nPartBlk = (E + PCHUNK - 1) / PCHUNK;
    int nPooled4 = n_graphs * CH / 4;
    int nZeroBlk = (nPooled4 + 255) / 256;
    WPtrs wp;
    for (int l = 0; l < 3; ++l) {
        wp.s[2 * l] = w1[l];     wp.d[2 * l] = wt[2 * l];
        wp.s[2 * l + 1] = w2[l]; wp.d[2 * l + 1] = wt[2 * l + 1];
    }
    prep_part_kernel<<<nPartBlk + nConvBlk + 384 + nZeroBlk, 256, 0, stream>>>(
        src, dst, bucketCnt, pairs, E, nPartBlk,
        (const float4*)x, (uint2*)xb, n4, nConvBlk, wp,
        (uint4*)pooled, nPooled4);

    build_csr_kernel<<<NB, 512, 0, stream>>>(pairs, bucketCnt, offs, csr, N);

    int fblk = (N + FBM - 1) / FBM;

    // three fused GIN layers
    fused_gin_kernel<0, 1, 0><<<fblk, 512, 0, stream>>>((const uint4*)xb, offs, csr,
        wt[0], b1[0], wt[1], b2[0], hA, batch, pooled, N);
    fused_gin_kernel<1, 1, 0><<<fblk, 512, 0, stream>>>((const uint4*)hA, offs, csr,
        wt[2], b1[1], wt[3], b2[1], hB, batch, pooled, N);
    fused_gin_kernel<2, 0, 1><<<fblk, 512, 0, stream>>>((const uint4*)hB, offs, csr,
        wt[4], b1[2], wt[5], b2[2], (unsigned short*)nullptr, batch, pooled, N);

    final_linear_kernel<<<n_graphs, CH, 0, stream>>>(pooled, lin_w, lin_b, out);
}